// Round 2
// baseline (2039.924 us; speedup 1.0000x reference)
//
#include <hip/hip_runtime.h>
#include <stdint.h>

#define ALPHA 0.1f
#define NN 20000
#define DF 768
#define NE 200000
#define NB 64
#define TSEQ 128
#define SF 128
#define HS 512
#define NCLS 14

typedef __attribute__((ext_vector_type(8))) short short8;
typedef __attribute__((ext_vector_type(4))) float f32x4;

// ---------------- workspace layout (bytes) ----------------
#define OFF_DEG     0u           // int[20000]
#define OFF_CSRC    80000u       // int[20000]
#define OFF_CNTB    160000u      // int[64]
#define OFF_FLAGS   160256u      // u32[16 groups][16 ranks][16] (64B per flag)
#define OFF_FLAG64  176640u      // int[1] : 1 if indices are int64
#define ZERO_INTS   44161u       // zero [0, 176644)
#define OFF_ROWPTR  176896u      // int[20001]
#define OFF_CURSOR  257024u      // int[20000]
#define OFF_DINV    337024u      // float[20000]
#define OFF_COL     417024u      // int[200000]
#define OFF_WGT     1217024u     // float[200000]
#define OFF_V0      2017280u     // float[20000*64]
#define OFF_V1      7137280u     // float[20000*64]
#define OFF_HBUF    12257280u    // bf16 [2][2][64][512]
#define OFF_YSEQ    12519424u    // float[64*1024]
#define OFF_SH1     12781568u    // float[64*512]
#define OFF_SH2     12912640u    // float[64*256]
#define OFF_PART    12978176u    // float[32][64][768]
#define OFF_POOL    19269632u    // float[64*768]
#define OFF_GH1     19466240u    // float[64*384]
#define OFF_GH2     19564544u    // float[64*192]

__device__ __forceinline__ unsigned short f2b(float f) {
  union { float f; unsigned u; } v; v.f = f;
  unsigned u = v.u;
  return (unsigned short)((u + 0x7FFFu + ((u >> 16) & 1u)) >> 16);
}

__device__ __forceinline__ int idx_at(const int* p, long long i, int mode64) {
  return mode64 ? p[2*i] : p[i];   // little-endian low word
}

// ---------------- small utility kernels ----------------
__global__ void zero_ints_kernel(int* p, int n) {
  int i = blockIdx.x * blockDim.x + threadIdx.x;
  if (i < n) p[i] = 0;
}

__global__ void detect_i64_kernel(const int* e, int* flag) {
  if (threadIdx.x == 0 && blockIdx.x == 0) {
    int all0 = 1;
    for (int i = 0; i < 256; ++i) if (e[2*i + 1] != 0) { all0 = 0; break; }
    *flag = all0;
  }
}

__global__ void hist_kernel(const int* e, const int* batch, int* deg, int* csrc,
                            int* cntb, const int* flag) {
  int i = blockIdx.x * blockDim.x + threadIdx.x;
  int m = *flag;
  if (i < NE) {
    int s = idx_at(e, i, m);
    int d = idx_at(e, (long long)NE + i, m);
    atomicAdd(&csrc[s], 1);
    atomicAdd(&deg[d], 1);
  }
  if (i < NN) atomicAdd(&cntb[idx_at(batch, i, m)], 1);
}

__global__ void dinv_kernel(const int* deg, float* dinv) {
  int i = blockIdx.x * blockDim.x + threadIdx.x;
  if (i < NN) dinv[i] = rsqrtf((float)(deg[i] + 1));   // +1 self loop, >=1
}

__global__ void scan_kernel(const int* cnt, int* row_ptr, int* cursor) {
  __shared__ int sA[1024], sB[1024];
  int tid = threadIdx.x;
  int carry = 0;
  const int nch = (NN + 1023) / 1024;
  for (int c = 0; c < nch; ++c) {
    int i = c * 1024 + tid;
    int v = (i < NN) ? cnt[i] : 0;
    sA[tid] = v;
    __syncthreads();
    int* src = sA; int* dst = sB;
    for (int off = 1; off < 1024; off <<= 1) {
      dst[tid] = src[tid] + (tid >= off ? src[tid - off] : 0);
      __syncthreads();
      int* t = src; src = dst; dst = t;
    }
    if (i < NN) { int ex = carry + src[tid] - v; row_ptr[i] = ex; cursor[i] = ex; }
    carry += src[1023];
    __syncthreads();
  }
  if (tid == 0) row_ptr[NN] = carry;
}

__global__ void fill_kernel(const int* e, const float* dinv, int* cursor,
                            int* colA, float* wgt, const int* flag) {
  int i = blockIdx.x * blockDim.x + threadIdx.x;
  if (i >= NE) return;
  int m = *flag;
  int s = idx_at(e, i, m);
  int d = idx_at(e, (long long)NE + i, m);
  int pos = atomicAdd(&cursor[s], 1);
  colA[pos] = d;
  wgt[pos] = dinv[s] * dinv[d];
}

__global__ void v0init_kernel(const int* batch, float* v0, const int* flag) {
  int i = blockIdx.x * blockDim.x + threadIdx.x;
  if (i >= NN * 64) return;
  int n = i >> 6, b = i & 63;
  v0[i] = (idx_at(batch, n, *flag) == b) ? 1.0f : 0.0f;
}

// one wave per node, lane = graph id (64 == wave width); 4-edge ILP
__global__ void hop_kernel(const float* __restrict__ vin, float* __restrict__ vout,
                           const int* __restrict__ row_ptr, const int* __restrict__ colA,
                           const float* __restrict__ wgt, const float* __restrict__ dinv,
                           const int* __restrict__ batch, const int* __restrict__ flag) {
  int wid = (blockIdx.x * blockDim.x + threadIdx.x) >> 6;
  int lane = threadIdx.x & 63;
  if (wid >= NN) return;
  float di = dinv[wid];
  float acc = di * di * vin[wid * 64 + lane];
  int e0 = row_ptr[wid], e1 = row_ptr[wid + 1];
  int e = e0;
  for (; e + 4 <= e1; e += 4) {
    int c0 = colA[e], c1 = colA[e + 1], c2 = colA[e + 2], c3 = colA[e + 3];
    float w0 = wgt[e], w1 = wgt[e + 1], w2 = wgt[e + 2], w3 = wgt[e + 3];
    float v0 = vin[(size_t)c0 * 64 + lane];
    float v1 = vin[(size_t)c1 * 64 + lane];
    float v2 = vin[(size_t)c2 * 64 + lane];
    float v3 = vin[(size_t)c3 * 64 + lane];
    acc += w0 * v0 + w1 * v1 + w2 * v2 + w3 * v3;
  }
  for (; e < e1; ++e) acc += wgt[e] * vin[(size_t)colA[e] * 64 + lane];
  float y0 = (idx_at(batch, wid, *flag) == lane) ? ALPHA : 0.0f;
  vout[wid * 64 + lane] = (1.0f - ALPHA) * acc + y0;
}

// pooled_unnorm partials: 48 f-tiles x 32 node-chunks, lane = graph id
__global__ void spmm_kernel(const float* __restrict__ S, const float* __restrict__ x,
                            float* __restrict__ partial) {
  int wid = (blockIdx.x * blockDim.x + threadIdx.x) >> 6;   // 1536 waves
  int lane = threadIdx.x & 63;
  int ft = wid % 48, ch = wid / 48;
  if (ch >= 32) return;
  int f0 = ft * 16;
  int n0 = ch * 625, n1 = n0 + 625;
  float acc[16];
#pragma unroll
  for (int f = 0; f < 16; ++f) acc[f] = 0.0f;
  for (int n = n0; n < n1; ++n) {
    float sv = S[n * 64 + lane];
    const float* xr = x + (size_t)n * DF + f0;
#pragma unroll
    for (int f = 0; f < 16; ++f) acc[f] += sv * xr[f];
  }
  float* pr = partial + ((size_t)(ch * 64 + lane)) * DF + f0;
#pragma unroll
  for (int f = 0; f < 16; ++f) pr[f] = acc[f];
}

__global__ void reduce_pool_kernel(const float* __restrict__ partial, const int* __restrict__ cntb,
                                   float* __restrict__ pooled) {
  int i = blockIdx.x * blockDim.x + threadIdx.x;
  if (i >= 64 * DF) return;
  int b = i / DF, f = i - b * DF;
  float s = 0.0f;
  for (int c = 0; c < 32; ++c) s += partial[((size_t)(c * 64 + b)) * DF + f];
  int cnt = cntb[b]; if (cnt < 1) cnt = 1;
  pooled[i] = s / (float)cnt;
}

// C[M,N] = act(A[M,K] @ W[N,K]^T + bias), optionally accumulate into C
__global__ void mlp_layer_kernel(const float* __restrict__ A, const float* __restrict__ W,
                                 const float* __restrict__ bias, float* __restrict__ C,
                                 int M, int N, int K, int relu, int accum) {
  int i = blockIdx.x * blockDim.x + threadIdx.x;
  if (i >= M * N) return;
  int mrow = i / N, n = i - mrow * N;
  float acc = bias[n];
  const float4* a4 = (const float4*)(A + (size_t)mrow * K);
  const float4* w4 = (const float4*)(W + (size_t)n * K);
  int k4 = K >> 2;
#pragma unroll 4
  for (int k = 0; k < k4; ++k) {
    float4 av = a4[k], wv = w4[k];
    acc += av.x * wv.x + av.y * wv.y + av.z * wv.z + av.w * wv.w;
  }
  if (relu) acc = fmaxf(acc, 0.0f);
  if (accum) C[i] += acc; else C[i] = acc;
}

// ---------------- GRU recurrent kernel ----------------
// grid 256 blocks x 384 thr. 16 groups x 16 ranks. group: dir=g>>3, seqs (g&7)*8..+8
// rank owns gate columns j0=rank*32 .. +32 (for r,z,n). Weights stationary in LDS (bf16).
// LDS: W1[96][672]: rows 0..63 = [Whh_r|Wih_r ; Whh_z|Wih_z] (K=640), rows 64..95 = Whh_n (K=512)
//      W2[32][136]: Wih_n (K=128)
//      hl[16][672]: rows 0..7 = [h | x_t] bf16, rows 8..15 scratch (gh staging floats)
// Exchange: per-rank 64B-padded flags (no RMW contention), x(t+1) prefetched
// during the gates phase so its latency overlaps the h-store drain.
#define GRU_LDS_BYTES 159232

__global__ __launch_bounds__(384, 1) void gru_kernel(
    const float* __restrict__ seq,
    const float* __restrict__ wih_f, const float* __restrict__ whh_f,
    const float* __restrict__ bih_f, const float* __restrict__ bhh_f,
    const float* __restrict__ wih_b, const float* __restrict__ whh_b,
    const float* __restrict__ bih_b, const float* __restrict__ bhh_b,
    unsigned* __restrict__ flags, unsigned short* __restrict__ hbuf,
    float* __restrict__ y_seq) {
  extern __shared__ char smem_raw[];
  unsigned short* W1 = (unsigned short*)smem_raw;       // 96*672
  unsigned short* W2 = W1 + 96 * 672;                   // 32*136
  unsigned short* hl = W2 + 32 * 136;                   // 16*672
  float* ghs = (float*)(hl + 8 * 672);                  // [128][8]

  const int tid = threadIdx.x;
  const int wave = tid >> 6, lane = tid & 63;
  const int g = blockIdx.x >> 4, rk = blockIdx.x & 15;
  const int d = g >> 3;
  const int seqbase = (g & 7) * 8;
  const int j0 = rk * 32;

  const float* wih = d ? wih_b : wih_f;
  const float* whh = d ? whh_b : whh_f;
  const float* bih = d ? bih_b : bih_f;
  const float* bhh = d ? bhh_b : bhh_f;

  // load stationary weights -> LDS (fp32 -> bf16)
  for (int idx = tid; idx < 96 * 640; idx += 384) {
    int row = idx / 640, c = idx - row * 640;
    float val;
    if (row < 64) {
      int gcol = (row < 32) ? (j0 + row) : (512 + j0 + row - 32);
      val = (c < 512) ? whh[gcol * 512 + c] : wih[gcol * 128 + (c - 512)];
    } else {
      int gcol = 1024 + j0 + (row - 64);
      val = (c < 512) ? whh[gcol * 512 + c] : 0.0f;
    }
    W1[row * 672 + c] = f2b(val);
  }
  for (int idx = tid; idx < 32 * 128; idx += 384) {
    int row = idx >> 7, c = idx & 127;
    W2[row * 136 + c] = f2b(wih[(1024 + j0 + row) * 128 + c]);
  }
  for (int idx = tid; idx < 8 * 512; idx += 384) {   // h(0) = 0
    int s = idx >> 9, c = idx & 511;
    hl[s * 672 + c] = 0;
  }
  {  // stage x(0)
    int tt0 = d ? 127 : 0;
#pragma unroll
    for (int i = 0; i < 3; ++i) {
      int flat = tid + 384 * i;
      if (flat < 1024) {
        int s = flat >> 7, k = flat & 127;
        hl[s * 672 + 512 + k] = f2b(seq[(size_t)(seqbase + s) * (TSEQ * SF) + tt0 * SF + k]);
      }
    }
  }

  float bias_r = 0, bias_z = 0, bihn = 0, bhhn = 0;
  float hprev = 0, msum = 0, mx = -1e30f;
  int seq_i = 0, col_i = 0;
  if (tid < 256) {
    seq_i = tid >> 5; col_i = tid & 31;
    bias_r = bih[j0 + col_i] + bhh[j0 + col_i];
    bias_z = bih[512 + j0 + col_i] + bhh[512 + j0 + col_i];
    bihn = bih[1024 + j0 + col_i];
    bhhn = bhh[1024 + j0 + col_i];
  }
  __syncthreads();

  const int quad = lane >> 4, l15 = lane & 15;

  for (int t = 0; t < 128; ++t) {
    // ---- GEMM on h(t)|x(t) ----
    f32x4 acc0 = {0, 0, 0, 0}, acc1 = {0, 0, 0, 0};
    const unsigned short* arow = hl + l15 * 672 + quad * 8;
    if (wave < 4) {        // fused r,z gates: K = 640 (h | x)
      const unsigned short* brow = W1 + (wave * 16 + l15) * 672 + quad * 8;
#pragma unroll
      for (int kc = 0; kc < 20; ++kc) {
        short8 a = *(const short8*)(arow + kc * 32);
        short8 b = *(const short8*)(brow + kc * 32);
        acc0 = __builtin_amdgcn_mfma_f32_16x16x32_bf16(a, b, acc0, 0, 0, 0);
      }
    } else {               // gh_n (K=512) and gi_n (K=128) separately
      const unsigned short* brow = W1 + (64 + (wave - 4) * 16 + l15) * 672 + quad * 8;
#pragma unroll
      for (int kc = 0; kc < 16; ++kc) {
        short8 a = *(const short8*)(arow + kc * 32);
        short8 b = *(const short8*)(brow + kc * 32);
        acc0 = __builtin_amdgcn_mfma_f32_16x16x32_bf16(a, b, acc0, 0, 0, 0);
      }
      const unsigned short* brow2 = W2 + ((wave - 4) * 16 + l15) * 136 + quad * 8;
#pragma unroll
      for (int kc = 0; kc < 4; ++kc) {
        short8 a = *(const short8*)(arow + 512 + kc * 32);
        short8 b = *(const short8*)(brow2 + kc * 32);
        acc1 = __builtin_amdgcn_mfma_f32_16x16x32_bf16(a, b, acc1, 0, 0, 0);
      }
    }
    __syncthreads();   // GEMM done; hl rows 8..15 reusable as gh staging
    if (wave < 4) {
      int row = wave * 16 + l15;
#pragma unroll
      for (int rr = 0; rr < 4; ++rr) {
        int m = quad * 4 + rr;
        if (m < 8) ghs[row * 8 + m] = acc0[rr];
      }
    } else {
      int rowg = 64 + (wave - 4) * 16 + l15;
      int rowi = 96 + (wave - 4) * 16 + l15;
#pragma unroll
      for (int rr = 0; rr < 4; ++rr) {
        int m = quad * 4 + rr;
        if (m < 8) { ghs[rowg * 8 + m] = acc0[rr]; ghs[rowi * 8 + m] = acc1[rr]; }
      }
    }
    __syncthreads();

    // ---- prefetch x(t+1) into regs (off the critical path) ----
    float xv[3] = {0, 0, 0};
    const int t1 = t + 1;
    if (t1 < 128) {
      int tt = d ? (127 - t1) : t1;
#pragma unroll
      for (int i = 0; i < 3; ++i) {
        int flat = tid + 384 * i;
        if (flat < 1024) {
          int s = flat >> 7, k = flat & 127;
          xv[i] = seq[(size_t)(seqbase + s) * (TSEQ * SF) + tt * SF + k];
        }
      }
    }

    // ---- gates for (seq_i, col_i) ----
    if (tid < 256) {
      float gr = ghs[col_i * 8 + seq_i];
      float gz = ghs[(32 + col_i) * 8 + seq_i];
      float gn = ghs[(64 + col_i) * 8 + seq_i];
      float gi = ghs[(96 + col_i) * 8 + seq_i];
      float r = 1.0f / (1.0f + __expf(-(gr + bias_r)));
      float z = 1.0f / (1.0f + __expf(-(gz + bias_z)));
      float narg = gi + bihn + r * (gn + bhhn);
      float e2 = __expf(-2.0f * fabsf(narg));
      float nt = (1.0f - e2) / (1.0f + e2);
      nt = (narg < 0.0f) ? -nt : nt;
      float h2 = (1.0f - z) * nt + z * hprev;
      hprev = h2; msum += h2; mx = fmaxf(mx, h2);
      if (t < 127) {
        float other = __shfl_down(h2, 1);
        if ((tid & 1) == 0) {
          unsigned pk = (unsigned)f2b(h2) | ((unsigned)f2b(other) << 16);
          unsigned* dst = (unsigned*)hbuf +
              (((( (t & 1) * 2 + d) * 64 + seqbase + seq_i) * 256) + ((j0 + col_i) >> 1));
          __hip_atomic_store(dst, pk, __ATOMIC_RELAXED, __HIP_MEMORY_SCOPE_AGENT);
        }
      }
    }

    // ---- write x(t+1) into hl (overlaps with h-store drain) ----
    if (t1 < 128) {
#pragma unroll
      for (int i = 0; i < 3; ++i) {
        int flat = tid + 384 * i;
        if (flat < 1024) {
          int s = flat >> 7, k = flat & 127;
          hl[s * 672 + 512 + k] = f2b(xv[i]);
        }
      }
    }
    __syncthreads();   // drains h atomic stores (vmcnt0 before barrier)

    if (t < 127) {
      // ---- per-rank flag release + poll (wave 0) ----
      if (wave == 0) {
        if (lane == 0) {
          __hip_atomic_store(&flags[(g * 16 + rk) * 16], (unsigned)(t + 1),
                             __ATOMIC_RELEASE, __HIP_MEMORY_SCOPE_AGENT);
        }
        if (lane < 16) {
          unsigned* f = &flags[(g * 16 + lane) * 16];
          int guard = 0;
          while (__hip_atomic_load(f, __ATOMIC_ACQUIRE, __HIP_MEMORY_SCOPE_AGENT)
                 < (unsigned)(t + 1)) {
            if (++guard > (1 << 20)) break;   // safety: wrong answer beats a hang
          }
        }
      }
      __syncthreads();
      // ---- gather full h(t+1) for the group (bf16, 8 seq x 512) ----
      const unsigned long long* hb64 = (const unsigned long long*)hbuf;
#pragma unroll
      for (int i = 0; i < 3; ++i) {
        int flat = tid + 384 * i;
        if (flat < 1024) {
          int s = flat >> 7, idx = flat & 127;
          unsigned long long v = __hip_atomic_load(
              hb64 + ((((t & 1) * 2 + d) * 64 + seqbase + s) * 128 + idx),
              __ATOMIC_RELAXED, __HIP_MEMORY_SCOPE_AGENT);
          *(unsigned long long*)(hl + s * 672 + idx * 4) = v;
        }
      }
      __syncthreads();
    }
  }

  if (tid < 256) {   // seq1 + seq2 = mean + max over T
    y_seq[(size_t)(seqbase + seq_i) * 1024 + d * 512 + j0 + col_i] =
        msum * (1.0f / 128.0f) + mx;
  }
}

// ---------------- launcher ----------------
extern "C" void kernel_launch(void* const* d_in, const int* in_sizes, int n_in,
                              void* d_out, int out_size, void* d_ws, size_t ws_size,
                              hipStream_t stream) {
  const float* x      = (const float*)d_in[0];
  const int*   eidx   = (const int*)d_in[1];
  const float* seq    = (const float*)d_in[2];
  const int*   batch  = (const int*)d_in[3];
  const float* wih_f  = (const float*)d_in[4];
  const float* whh_f  = (const float*)d_in[5];
  const float* bih_f  = (const float*)d_in[6];
  const float* bhh_f  = (const float*)d_in[7];
  const float* wih_b  = (const float*)d_in[8];
  const float* whh_b  = (const float*)d_in[9];
  const float* bih_b  = (const float*)d_in[10];
  const float* bhh_b  = (const float*)d_in[11];
  const float* mg_w0  = (const float*)d_in[12];
  const float* mg_b0  = (const float*)d_in[13];
  const float* mg_w1  = (const float*)d_in[14];
  const float* mg_b1  = (const float*)d_in[15];
  const float* mg_w2  = (const float*)d_in[16];
  const float* mg_b2  = (const float*)d_in[17];
  const float* ms_w0  = (const float*)d_in[18];
  const float* ms_b0  = (const float*)d_in[19];
  const float* ms_w1  = (const float*)d_in[20];
  const float* ms_b1  = (const float*)d_in[21];
  const float* ms_w2  = (const float*)d_in[22];
  const float* ms_b2  = (const float*)d_in[23];
  float* out = (float*)d_out;
  char* ws = (char*)d_ws;

  int*   deg     = (int*)(ws + OFF_DEG);
  int*   csrc    = (int*)(ws + OFF_CSRC);
  int*   cntb    = (int*)(ws + OFF_CNTB);
  unsigned* flg  = (unsigned*)(ws + OFF_FLAGS);
  int*   flag    = (int*)(ws + OFF_FLAG64);
  int*   row_ptr = (int*)(ws + OFF_ROWPTR);
  int*   cursor  = (int*)(ws + OFF_CURSOR);
  float* dinv    = (float*)(ws + OFF_DINV);
  int*   colA    = (int*)(ws + OFF_COL);
  float* wgtA    = (float*)(ws + OFF_WGT);
  float* V0      = (float*)(ws + OFF_V0);
  float* V1      = (float*)(ws + OFF_V1);
  unsigned short* hbuf = (unsigned short*)(ws + OFF_HBUF);
  float* y_seq   = (float*)(ws + OFF_YSEQ);
  float* sh1     = (float*)(ws + OFF_SH1);
  float* sh2     = (float*)(ws + OFF_SH2);
  float* part    = (float*)(ws + OFF_PART);
  float* pooled  = (float*)(ws + OFF_POOL);
  float* gh1     = (float*)(ws + OFF_GH1);
  float* gh2     = (float*)(ws + OFF_GH2);

  hipFuncSetAttribute((const void*)gru_kernel,
                      hipFuncAttributeMaxDynamicSharedMemorySize, GRU_LDS_BYTES);

  // ---- graph prep (CSR for A^T, degrees, batch counts) ----
  zero_ints_kernel<<<(ZERO_INTS + 255) / 256, 256, 0, stream>>>((int*)ws, (int)ZERO_INTS);
  detect_i64_kernel<<<1, 64, 0, stream>>>(eidx, flag);
  hist_kernel<<<(NE + 255) / 256, 256, 0, stream>>>(eidx, batch, deg, csrc, cntb, flag);
  dinv_kernel<<<(NN + 255) / 256, 256, 0, stream>>>(deg, dinv);
  scan_kernel<<<1, 1024, 0, stream>>>(csrc, row_ptr, cursor);
  fill_kernel<<<(NE + 255) / 256, 256, 0, stream>>>(eidx, dinv, cursor, colA, wgtA, flag);
  v0init_kernel<<<(NN * 64 + 255) / 256, 256, 0, stream>>>(batch, V0, flag);

  // ---- APPNP, transposed: propagate 64-wide pooling coefficients ----
  for (int h = 0; h < 16; ++h) {
    const float* vin = (h & 1) ? V1 : V0;
    float* vout = (h & 1) ? V0 : V1;
    hop_kernel<<<(NN * 64 + 255) / 256, 256, 0, stream>>>(vin, vout, row_ptr, colA,
                                                          wgtA, dinv, batch, flag);
  }

  // ---- BiGRU (fused gi + recurrent + pooling) ----
  gru_kernel<<<256, 384, GRU_LDS_BYTES, stream>>>(
      seq, wih_f, whh_f, bih_f, bhh_f, wih_b, whh_b, bih_b, bhh_b, flg, hbuf, y_seq);

  // ---- seq MLP: 1024 -> 512 -> 256 -> 14 (writes d_out) ----
  mlp_layer_kernel<<<(64 * 512 + 255) / 256, 256, 0, stream>>>(y_seq, ms_w0, ms_b0, sh1,
                                                               64, 512, 1024, 1, 0);
  mlp_layer_kernel<<<(64 * 256 + 255) / 256, 256, 0, stream>>>(sh1, ms_w1, ms_b1, sh2,
                                                               64, 256, 512, 1, 0);
  mlp_layer_kernel<<<(64 * NCLS + 255) / 256, 256, 0, stream>>>(sh2, ms_w2, ms_b2, out,
                                                                64, NCLS, 256, 0, 0);

  // ---- pooled = (S^T x) / cnt ; after 16 hops result is in V0 ----
  spmm_kernel<<<(1536 * 64) / 256, 256, 0, stream>>>(V0, x, part);
  reduce_pool_kernel<<<(64 * DF + 255) / 256, 256, 0, stream>>>(part, cntb, pooled);

  // ---- graph MLP: 768 -> 384 -> 192 -> 14 (accumulates into d_out) ----
  mlp_layer_kernel<<<(64 * 384 + 255) / 256, 256, 0, stream>>>(pooled, mg_w0, mg_b0, gh1,
                                                               64, 384, 768, 1, 0);
  mlp_layer_kernel<<<(64 * 192 + 255) / 256, 256, 0, stream>>>(gh1, mg_w1, mg_b1, gh2,
                                                               64, 192, 384, 1, 0);
  mlp_layer_kernel<<<(64 * NCLS + 255) / 256, 256, 0, stream>>>(gh2, mg_w2, mg_b2, out,
                                                                64, NCLS, 192, 0, 1);
  (void)in_sizes; (void)n_in; (void)out_size; (void)ws_size;
}

// Round 3
// 1746.441 us; speedup vs baseline: 1.1680x; 1.1680x over previous
//
#include <hip/hip_runtime.h>
#include <stdint.h>

#define ALPHA 0.1f
#define NN 20000
#define DF 768
#define NE 200000
#define NB 64
#define TSEQ 128
#define SF 128
#define HS 512
#define NCLS 14

typedef __attribute__((ext_vector_type(8))) short short8;
typedef __attribute__((ext_vector_type(4))) float f32x4;

// ---------------- workspace layout (bytes) ----------------
#define OFF_DEG     0u           // int[20000]
#define OFF_CSRC    80000u       // int[20000]
#define OFF_CNTB    160000u      // int[64]
#define OFF_FLAG64  176640u      // int[1] : 1 if indices are int64
#define ZERO_INTS   44161u       // zero [0, 176644)
#define OFF_ROWPTR  176896u      // int[20001]
#define OFF_CURSOR  257024u      // int[20000]
#define OFF_DINV    337024u      // float[20000]
#define OFF_COL     417024u      // int[200000]
#define OFF_WGT     1217024u     // float[200000]
#define OFF_V0      2017280u     // float[20000*64]
#define OFF_V1      7137280u     // float[20000*64]
#define OFF_HBUF    12257280u    // u32 [2][2][64][512]  (tag<<16 | bf16 h)
#define OFF_YSEQ    12781568u    // float[64*1024]
#define OFF_SH1     13043712u    // float[64*512]
#define OFF_SH2     13174784u    // float[64*256]
#define OFF_PART    13240320u    // float[16][64][768]
#define OFF_POOL    16386048u    // float[64*768]
#define OFF_GH1     16582656u    // float[64*384]
#define OFF_GH2     16680960u    // float[64*192]

__device__ __forceinline__ unsigned short f2b(float f) {
  union { float f; unsigned u; } v; v.f = f;
  unsigned u = v.u;
  return (unsigned short)((u + 0x7FFFu + ((u >> 16) & 1u)) >> 16);
}

__device__ __forceinline__ int idx_at(const int* p, long long i, int mode64) {
  return mode64 ? p[2*i] : p[i];   // little-endian low word
}

// ---------------- small utility kernels ----------------
__global__ void zero_ints_kernel(int* p, int n) {
  int i = blockIdx.x * blockDim.x + threadIdx.x;
  if (i < n) p[i] = 0;
}

__global__ void detect_i64_kernel(const int* e, int* flag) {
  if (threadIdx.x == 0 && blockIdx.x == 0) {
    int all0 = 1;
    for (int i = 0; i < 256; ++i) if (e[2*i + 1] != 0) { all0 = 0; break; }
    *flag = all0;
  }
}

__global__ void hist_kernel(const int* e, const int* batch, int* deg, int* csrc,
                            int* cntb, const int* flag) {
  int i = blockIdx.x * blockDim.x + threadIdx.x;
  int m = *flag;
  if (i < NE) {
    int s = idx_at(e, i, m);
    int d = idx_at(e, (long long)NE + i, m);
    atomicAdd(&csrc[s], 1);
    atomicAdd(&deg[d], 1);
  }
  if (i < NN) atomicAdd(&cntb[idx_at(batch, i, m)], 1);
}

__global__ void dinv_kernel(const int* deg, float* dinv) {
  int i = blockIdx.x * blockDim.x + threadIdx.x;
  if (i < NN) dinv[i] = rsqrtf((float)(deg[i] + 1));   // +1 self loop, >=1
}

__global__ void scan_kernel(const int* cnt, int* row_ptr, int* cursor) {
  __shared__ int sA[1024], sB[1024];
  int tid = threadIdx.x;
  int carry = 0;
  const int nch = (NN + 1023) / 1024;
  for (int c = 0; c < nch; ++c) {
    int i = c * 1024 + tid;
    int v = (i < NN) ? cnt[i] : 0;
    sA[tid] = v;
    __syncthreads();
    int* src = sA; int* dst = sB;
    for (int off = 1; off < 1024; off <<= 1) {
      dst[tid] = src[tid] + (tid >= off ? src[tid - off] : 0);
      __syncthreads();
      int* t = src; src = dst; dst = t;
    }
    if (i < NN) { int ex = carry + src[tid] - v; row_ptr[i] = ex; cursor[i] = ex; }
    carry += src[1023];
    __syncthreads();
  }
  if (tid == 0) row_ptr[NN] = carry;
}

__global__ void fill_kernel(const int* e, const float* dinv, int* cursor,
                            int* colA, float* wgt, const int* flag) {
  int i = blockIdx.x * blockDim.x + threadIdx.x;
  if (i >= NE) return;
  int m = *flag;
  int s = idx_at(e, i, m);
  int d = idx_at(e, (long long)NE + i, m);
  int pos = atomicAdd(&cursor[s], 1);
  colA[pos] = d;
  wgt[pos] = dinv[s] * dinv[d];
}

__global__ void v0init_kernel(const int* batch, float* v0, const int* flag) {
  int i = blockIdx.x * blockDim.x + threadIdx.x;
  if (i >= NN * 64) return;
  int n = i >> 6, b = i & 63;
  v0[i] = (idx_at(batch, n, *flag) == b) ? 1.0f : 0.0f;
}

// one wave per node, lane = graph id (64 == wave width); 4-edge ILP
__global__ void hop_kernel(const float* __restrict__ vin, float* __restrict__ vout,
                           const int* __restrict__ row_ptr, const int* __restrict__ colA,
                           const float* __restrict__ wgt, const float* __restrict__ dinv,
                           const int* __restrict__ batch, const int* __restrict__ flag) {
  int wid = (blockIdx.x * blockDim.x + threadIdx.x) >> 6;
  int lane = threadIdx.x & 63;
  if (wid >= NN) return;
  float di = dinv[wid];
  float acc = di * di * vin[wid * 64 + lane];
  int e0 = row_ptr[wid], e1 = row_ptr[wid + 1];
  int e = e0;
  for (; e + 4 <= e1; e += 4) {
    int c0 = colA[e], c1 = colA[e + 1], c2 = colA[e + 2], c3 = colA[e + 3];
    float w0 = wgt[e], w1 = wgt[e + 1], w2 = wgt[e + 2], w3 = wgt[e + 3];
    float v0 = vin[(size_t)c0 * 64 + lane];
    float v1 = vin[(size_t)c1 * 64 + lane];
    float v2 = vin[(size_t)c2 * 64 + lane];
    float v3 = vin[(size_t)c3 * 64 + lane];
    acc += w0 * v0 + w1 * v1 + w2 * v2 + w3 * v3;
  }
  for (; e < e1; ++e) acc += wgt[e] * vin[(size_t)colA[e] * 64 + lane];
  float y0 = (idx_at(batch, wid, *flag) == lane) ? ALPHA : 0.0f;
  vout[wid * 64 + lane] = (1.0f - ALPHA) * acc + y0;
}

// pooled_unnorm partials: 48 f-tiles x 16 node-chunks, lane = graph id
__global__ void spmm_kernel(const float* __restrict__ S, const float* __restrict__ x,
                            float* __restrict__ partial) {
  int wid = (blockIdx.x * blockDim.x + threadIdx.x) >> 6;   // 768 waves
  int lane = threadIdx.x & 63;
  int ft = wid % 48, ch = wid / 48;
  if (ch >= 16) return;
  int f0 = ft * 16;
  int n0 = ch * 1250, n1 = n0 + 1250;
  float acc[16];
#pragma unroll
  for (int f = 0; f < 16; ++f) acc[f] = 0.0f;
  for (int n = n0; n < n1; ++n) {
    float sv = S[n * 64 + lane];
    const float* xr = x + (size_t)n * DF + f0;
#pragma unroll
    for (int f = 0; f < 16; ++f) acc[f] += sv * xr[f];
  }
  float* pr = partial + ((size_t)(ch * 64 + lane)) * DF + f0;
#pragma unroll
  for (int f = 0; f < 16; ++f) pr[f] = acc[f];
}

__global__ void reduce_pool_kernel(const float* __restrict__ partial, const int* __restrict__ cntb,
                                   float* __restrict__ pooled) {
  int i = blockIdx.x * blockDim.x + threadIdx.x;
  if (i >= 64 * DF) return;
  int b = i / DF, f = i - b * DF;
  float s = 0.0f;
  for (int c = 0; c < 16; ++c) s += partial[((size_t)(c * 64 + b)) * DF + f];
  int cnt = cntb[b]; if (cnt < 1) cnt = 1;
  pooled[i] = s / (float)cnt;
}

// C[M,N] = act(A[M,K] @ W[N,K]^T + bias), optionally accumulate into C
__global__ void mlp_layer_kernel(const float* __restrict__ A, const float* __restrict__ W,
                                 const float* __restrict__ bias, float* __restrict__ C,
                                 int M, int N, int K, int relu, int accum) {
  int i = blockIdx.x * blockDim.x + threadIdx.x;
  if (i >= M * N) return;
  int mrow = i / N, n = i - mrow * N;
  float acc = bias[n];
  const float4* a4 = (const float4*)(A + (size_t)mrow * K);
  const float4* w4 = (const float4*)(W + (size_t)n * K);
  int k4 = K >> 2;
#pragma unroll 4
  for (int k = 0; k < k4; ++k) {
    float4 av = a4[k], wv = w4[k];
    acc += av.x * wv.x + av.y * wv.y + av.z * wv.z + av.w * wv.w;
  }
  if (relu) acc = fmaxf(acc, 0.0f);
  if (accum) C[i] += acc; else C[i] = acc;
}

// ---------------- GRU recurrent kernel (staggered fwd/bwd, tagged exchange) --
// 256 blocks = 8 groups (8 seqs each) x 32 ranks (16 h-cols per dir each).
// Each block holds BOTH directions' weight slices in LDS:
//   W1[2][48][648] bf16: rows 0..15 = [Whh_r|Wih_r] (K=640), 16..31 = z,
//                        32..47 = [Whh_n|Wih_n] (n-gate h-part K=512 and
//                        x-part K=128 accumulated separately).
//   hl[2][8][648] bf16: per-dir [h(512) | x(128)] A-rows (8 seqs).
//   ghs[2][64][8] f32: gate staging (r,z,n_h,n_x) x 16 cols x 8 seqs.
// Exchange: h stored to hbuf as (tag<<16)|bf16 via relaxed agent atomics,
// double-buffered on t&1; consumers poll tags directly (no flags, no drains).
// Stagger: phase1 = GEMM_fwd || gather_bwd; phase2 = GEMM_bwd || gather_fwd,
// so each dir's MALL latency hides behind the other dir's MFMA work.
#define GRU_LDS_BYTES 155648

__global__ __launch_bounds__(384, 1) void gru_kernel(
    const float* __restrict__ seq,
    const float* __restrict__ wih_f, const float* __restrict__ whh_f,
    const float* __restrict__ bih_f, const float* __restrict__ bhh_f,
    const float* __restrict__ wih_b, const float* __restrict__ whh_b,
    const float* __restrict__ bih_b, const float* __restrict__ bhh_b,
    unsigned* __restrict__ hbuf, float* __restrict__ y_seq) {
  extern __shared__ char smem_raw[];
  unsigned short* W1 = (unsigned short*)smem_raw;     // [2][48][648]
  unsigned short* hl = W1 + 2 * 48 * 648;             // [2][8][648]
  float* ghs = (float*)(hl + 2 * 8 * 648);            // [2][64][8]

  const int tid = threadIdx.x;
  const int wave = tid >> 6, lane = tid & 63;
  const int quad = lane >> 4, l15 = lane & 15;
  const int g = blockIdx.x >> 5;          // 8 groups
  const int rk = blockIdx.x & 31;         // 32 ranks
  const int seqbase = g * 8;
  const int c0 = rk * 16;

  const float* WHH[2] = {whh_f, whh_b};
  const float* WIH[2] = {wih_f, wih_b};
  const float* BIH[2] = {bih_f, bih_b};
  const float* BHH[2] = {bhh_f, bhh_b};

  // ---- stationary weights -> LDS (fp32 -> bf16) ----
  for (int i = tid; i < 2 * 48 * 640; i += 384) {
    int d = i / 30720;
    int rrow = (i - d * 30720) / 640;
    int c = i - d * 30720 - rrow * 640;
    int gcol = (rrow < 16) ? (c0 + rrow)
             : (rrow < 32) ? (512 + c0 + (rrow - 16))
                           : (1024 + c0 + (rrow - 32));
    float val = (c < 512) ? WHH[d][gcol * 512 + c] : WIH[d][gcol * 128 + (c - 512)];
    W1[(d * 48 + rrow) * 648 + c] = f2b(val);
  }
  // ---- hl init: h(0)=0; stage x(0) for both dirs ----
  for (int i = tid; i < 2 * 8 * 512; i += 384) {
    int d = i >> 12;
    int rem = i & 4095; int s = rem >> 9, c = rem & 511;
    hl[(d * 8 + s) * 648 + c] = 0;
  }
  for (int i = tid; i < 2 * 8 * 128; i += 384) {
    int d = i >> 10; int rem = i & 1023; int s = rem >> 7, k = rem & 127;
    int tt = d ? 127 : 0;
    hl[(d * 8 + s) * 648 + 512 + k] =
        f2b(seq[(size_t)(seqbase + s) * (TSEQ * SF) + tt * SF + k]);
  }

  float b_r[2] = {0, 0}, b_z[2] = {0, 0}, b_in[2] = {0, 0}, b_hn[2] = {0, 0};
  float hprev[2] = {0, 0}, msum[2] = {0, 0}, mx[2] = {-1e30f, -1e30f};
  const int seq_i = (tid >> 4) & 7, col_i = tid & 15;
  if (tid < 128) {
#pragma unroll
    for (int d = 0; d < 2; ++d) {
      b_r[d]  = BIH[d][c0 + col_i] + BHH[d][c0 + col_i];
      b_z[d]  = BIH[d][512 + c0 + col_i] + BHH[d][512 + c0 + col_i];
      b_in[d] = BIH[d][1024 + c0 + col_i];
      b_hn[d] = BHH[d][1024 + c0 + col_i];
    }
  }
  __syncthreads();

  auto do_gemm = [&](int d, int wrole) {
    f32x4 accH = {0, 0, 0, 0}, accX = {0, 0, 0, 0};
    const unsigned short* arow = hl + d * 5184 + l15 * 648 + quad * 8;
    const unsigned short* brow = W1 + d * 31104 + (wrole * 16 + l15) * 648 + quad * 8;
    if (wrole < 2) {          // r or z: fused K=640 over [h|x]
#pragma unroll
      for (int kc = 0; kc < 20; ++kc)
        accH = __builtin_amdgcn_mfma_f32_16x16x32_bf16(
            *(const short8*)(arow + kc * 32), *(const short8*)(brow + kc * 32),
            accH, 0, 0, 0);
      float* gd = ghs + d * 512 + (wrole * 16 + l15) * 8;
#pragma unroll
      for (int rr = 0; rr < 4; ++rr) { int m = quad * 4 + rr; if (m < 8) gd[m] = accH[rr]; }
    } else {                  // n: h-part (K=512) and x-part (K=128) separate
#pragma unroll
      for (int kc = 0; kc < 16; ++kc)
        accH = __builtin_amdgcn_mfma_f32_16x16x32_bf16(
            *(const short8*)(arow + kc * 32), *(const short8*)(brow + kc * 32),
            accH, 0, 0, 0);
#pragma unroll
      for (int kc = 0; kc < 4; ++kc)
        accX = __builtin_amdgcn_mfma_f32_16x16x32_bf16(
            *(const short8*)(arow + 512 + kc * 32), *(const short8*)(brow + 512 + kc * 32),
            accX, 0, 0, 0);
      float* gdh = ghs + d * 512 + (32 + l15) * 8;
      float* gdx = ghs + d * 512 + (48 + l15) * 8;
#pragma unroll
      for (int rr = 0; rr < 4; ++rr) {
        int m = quad * 4 + rr;
        if (m < 8) { gdh[m] = accH[rr]; gdx[m] = accX[rr]; }
      }
    }
  };

  // gather h(tag) for dir d into hl + stage x(t_x); run by 192 threads (l192)
  auto do_gather_stage = [&](int d, int t_x, int slot, unsigned tagexp, int l192) {
    // stage x first (independent global loads overlap the tag-poll)
    if (t_x >= 0 && t_x < 128) {
      int tt = d ? (127 - t_x) : t_x;
#pragma unroll
      for (int j = 0; j < 6; ++j) {
        int flat = l192 + 192 * j;
        if (flat < 1024) {
          int s = flat >> 7, k = flat & 127;
          hl[d * 5184 + s * 648 + 512 + k] =
              f2b(seq[(size_t)(seqbase + s) * (TSEQ * SF) + tt * SF + k]);
        }
      }
    }
    unsigned v[22];
    int guard = 0;
    for (;;) {
      int ok = 1;
#pragma unroll
      for (int j = 0; j < 22; ++j) {
        int flat = l192 + 192 * j;
        if (flat < 4096) {
          v[j] = __hip_atomic_load(
              &hbuf[((size_t)((slot * 2 + d) * 64 + seqbase + (flat >> 9))) * 512 +
                    (flat & 511)],
              __ATOMIC_RELAXED, __HIP_MEMORY_SCOPE_AGENT);
          ok &= (int)((v[j] >> 16) == tagexp);
        }
      }
      if (ok || ++guard > (1 << 18)) break;
      __builtin_amdgcn_s_sleep(1);
    }
#pragma unroll
    for (int j = 0; j < 22; ++j) {
      int flat = l192 + 192 * j;
      if (flat < 4096)
        hl[d * 5184 + (flat >> 9) * 648 + (flat & 511)] =
            (unsigned short)(v[j] & 0xFFFFu);
    }
  };

  auto do_gates = [&](int d, int t) {
    const float* gd = ghs + d * 512;
    float gr = gd[col_i * 8 + seq_i];
    float gz = gd[(16 + col_i) * 8 + seq_i];
    float gh = gd[(32 + col_i) * 8 + seq_i];
    float gx = gd[(48 + col_i) * 8 + seq_i];
    float r = 1.0f / (1.0f + __expf(-(gr + b_r[d])));
    float z = 1.0f / (1.0f + __expf(-(gz + b_z[d])));
    float narg = gx + b_in[d] + r * (gh + b_hn[d]);
    float e2 = __expf(-2.0f * fabsf(narg));
    float nt = (1.0f - e2) / (1.0f + e2);
    nt = (narg < 0.0f) ? -nt : nt;
    float h2 = (1.0f - z) * nt + z * hprev[d];
    hprev[d] = h2; msum[d] += h2; mx[d] = fmaxf(mx[d], h2);
    if (t < 127) {
      unsigned pk = ((unsigned)(t + 1) << 16) | (unsigned)f2b(h2);
      __hip_atomic_store(
          &hbuf[((size_t)(((((t + 1) & 1) * 2) + d) * 64 + seqbase + seq_i)) * 512 +
                (c0 + col_i)],
          pk, __ATOMIC_RELAXED, __HIP_MEMORY_SCOPE_AGENT);
    }
  };

  for (int t = 0; t < 128; ++t) {
    // phase 1: waves 0-2 GEMM fwd(t) ; waves 3-5 gather h_bwd(t) + stage x_bwd(t)
    if (wave < 3) do_gemm(0, wave);
    else if (t > 0) do_gather_stage(1, t, t & 1, (unsigned)t, tid - 192);
    __syncthreads();
    if (tid < 128) do_gates(0, t);
    // phase 2: waves 3-5 GEMM bwd(t) ; waves 0-2 gather h_fwd(t+1) + stage x_fwd(t+1)
    if (wave >= 3) do_gemm(1, wave - 3);
    else if (t < 127) do_gather_stage(0, t + 1, (t + 1) & 1, (unsigned)(t + 1), tid);
    __syncthreads();
    if (tid < 128) do_gates(1, t);
  }

  if (tid < 128) {   // seq1 + seq2 = mean + max over T
    y_seq[(size_t)(seqbase + seq_i) * 1024 + c0 + col_i] =
        msum[0] * (1.0f / 128.0f) + mx[0];
    y_seq[(size_t)(seqbase + seq_i) * 1024 + 512 + c0 + col_i] =
        msum[1] * (1.0f / 128.0f) + mx[1];
  }
}

// ---------------- launcher ----------------
extern "C" void kernel_launch(void* const* d_in, const int* in_sizes, int n_in,
                              void* d_out, int out_size, void* d_ws, size_t ws_size,
                              hipStream_t stream) {
  const float* x      = (const float*)d_in[0];
  const int*   eidx   = (const int*)d_in[1];
  const float* seq    = (const float*)d_in[2];
  const int*   batch  = (const int*)d_in[3];
  const float* wih_f  = (const float*)d_in[4];
  const float* whh_f  = (const float*)d_in[5];
  const float* bih_f  = (const float*)d_in[6];
  const float* bhh_f  = (const float*)d_in[7];
  const float* wih_b  = (const float*)d_in[8];
  const float* whh_b  = (const float*)d_in[9];
  const float* bih_b  = (const float*)d_in[10];
  const float* bhh_b  = (const float*)d_in[11];
  const float* mg_w0  = (const float*)d_in[12];
  const float* mg_b0  = (const float*)d_in[13];
  const float* mg_w1  = (const float*)d_in[14];
  const float* mg_b1  = (const float*)d_in[15];
  const float* mg_w2  = (const float*)d_in[16];
  const float* mg_b2  = (const float*)d_in[17];
  const float* ms_w0  = (const float*)d_in[18];
  const float* ms_b0  = (const float*)d_in[19];
  const float* ms_w1  = (const float*)d_in[20];
  const float* ms_b1  = (const float*)d_in[21];
  const float* ms_w2  = (const float*)d_in[22];
  const float* ms_b2  = (const float*)d_in[23];
  float* out = (float*)d_out;
  char* ws = (char*)d_ws;

  int*   deg     = (int*)(ws + OFF_DEG);
  int*   csrc    = (int*)(ws + OFF_CSRC);
  int*   cntb    = (int*)(ws + OFF_CNTB);
  int*   flag    = (int*)(ws + OFF_FLAG64);
  int*   row_ptr = (int*)(ws + OFF_ROWPTR);
  int*   cursor  = (int*)(ws + OFF_CURSOR);
  float* dinv    = (float*)(ws + OFF_DINV);
  int*   colA    = (int*)(ws + OFF_COL);
  float* wgtA    = (float*)(ws + OFF_WGT);
  float* V0      = (float*)(ws + OFF_V0);
  float* V1      = (float*)(ws + OFF_V1);
  unsigned* hbuf = (unsigned*)(ws + OFF_HBUF);
  float* y_seq   = (float*)(ws + OFF_YSEQ);
  float* sh1     = (float*)(ws + OFF_SH1);
  float* sh2     = (float*)(ws + OFF_SH2);
  float* part    = (float*)(ws + OFF_PART);
  float* pooled  = (float*)(ws + OFF_POOL);
  float* gh1     = (float*)(ws + OFF_GH1);
  float* gh2     = (float*)(ws + OFF_GH2);

  hipFuncSetAttribute((const void*)gru_kernel,
                      hipFuncAttributeMaxDynamicSharedMemorySize, GRU_LDS_BYTES);

  // ---- graph prep (CSR for A^T, degrees, batch counts) ----
  zero_ints_kernel<<<(ZERO_INTS + 255) / 256, 256, 0, stream>>>((int*)ws, (int)ZERO_INTS);
  detect_i64_kernel<<<1, 64, 0, stream>>>(eidx, flag);
  hist_kernel<<<(NE + 255) / 256, 256, 0, stream>>>(eidx, batch, deg, csrc, cntb, flag);
  dinv_kernel<<<(NN + 255) / 256, 256, 0, stream>>>(deg, dinv);
  scan_kernel<<<1, 1024, 0, stream>>>(csrc, row_ptr, cursor);
  fill_kernel<<<(NE + 255) / 256, 256, 0, stream>>>(eidx, dinv, cursor, colA, wgtA, flag);
  v0init_kernel<<<(NN * 64 + 255) / 256, 256, 0, stream>>>(batch, V0, flag);

  // ---- APPNP, transposed: propagate 64-wide pooling coefficients ----
  for (int h = 0; h < 16; ++h) {
    const float* vin = (h & 1) ? V1 : V0;
    float* vout = (h & 1) ? V0 : V1;
    hop_kernel<<<(NN * 64 + 255) / 256, 256, 0, stream>>>(vin, vout, row_ptr, colA,
                                                          wgtA, dinv, batch, flag);
  }

  // ---- BiGRU (fused gi + recurrent + pooling) ----
  gru_kernel<<<256, 384, GRU_LDS_BYTES, stream>>>(
      seq, wih_f, whh_f, bih_f, bhh_f, wih_b, whh_b, bih_b, bhh_b, hbuf, y_seq);

  // ---- seq MLP: 1024 -> 512 -> 256 -> 14 (writes d_out) ----
  mlp_layer_kernel<<<(64 * 512 + 255) / 256, 256, 0, stream>>>(y_seq, ms_w0, ms_b0, sh1,
                                                               64, 512, 1024, 1, 0);
  mlp_layer_kernel<<<(64 * 256 + 255) / 256, 256, 0, stream>>>(sh1, ms_w1, ms_b1, sh2,
                                                               64, 256, 512, 1, 0);
  mlp_layer_kernel<<<(64 * NCLS + 255) / 256, 256, 0, stream>>>(sh2, ms_w2, ms_b2, out,
                                                                64, NCLS, 256, 0, 0);

  // ---- pooled = (S^T x) / cnt ; after 16 hops result is in V0 ----
  spmm_kernel<<<(768 * 64) / 256, 256, 0, stream>>>(V0, x, part);
  reduce_pool_kernel<<<(64 * DF + 255) / 256, 256, 0, stream>>>(part, cntb, pooled);

  // ---- graph MLP: 768 -> 384 -> 192 -> 14 (accumulates into d_out) ----
  mlp_layer_kernel<<<(64 * 384 + 255) / 256, 256, 0, stream>>>(pooled, mg_w0, mg_b0, gh1,
                                                               64, 384, 768, 1, 0);
  mlp_layer_kernel<<<(64 * 192 + 255) / 256, 256, 0, stream>>>(gh1, mg_w1, mg_b1, gh2,
                                                               64, 192, 384, 1, 0);
  mlp_layer_kernel<<<(64 * NCLS + 255) / 256, 256, 0, stream>>>(gh2, mg_w2, mg_b2, out,
                                                                64, NCLS, 192, 0, 1);
  (void)in_sizes; (void)n_in; (void)out_size; (void)ws_size;
}